// Round 23
// baseline (179.833 us; speedup 1.0000x reference)
//
#include <hip/hip_runtime.h>
#include <math.h>

// Problem constants
#define BN_ 512     // B*NVARS
#define T_  128
#define C_  128
#define H_  8
#define D_  16
#define F_  256
#define M_  65536   // BN_*T_

typedef __bf16 bf16x8 __attribute__((ext_vector_type(8)));
typedef float f32x4 __attribute__((ext_vector_type(4)));
union U8 { uint2 d[2]; bf16x8 v; unsigned short u[8]; };

// native f32->bf16 (RNE) -- lets compiler emit v_cvt_pk_bf16_f32
__device__ inline unsigned short f2bf(float x) {
  union { __bf16 b; unsigned short u; } c;
  c.b = (__bf16)x;
  return c.u;
}
__device__ inline float bf2f(unsigned short h) {
  return __uint_as_float((unsigned int)h << 16);
}
// exact-enough GELU: erf via A&S 7.1.26, |eps|<=1.5e-7
__device__ inline float gelu_f(float x) {
  float z  = x * 0.70710678118654752f;
  float az = fabsf(z);
  float t  = 1.0f / (1.0f + 0.3275911f * az);
  float poly = ((((1.061405429f*t - 1.453152027f)*t + 1.421413741f)*t
                 - 0.284496736f)*t + 0.254829592f)*t;
  float e  = __expf(-z*z);
  float er = 1.0f - poly*e;
  er = (z < 0.0f) ? -er : er;
  return 0.5f * x * (1.0f + er);
}

// ---------------------------------------------------------------------------
// K-prep: FFN weight frags (blocks 0..63), E frags (64..71),
//         qkv_w split hi/lo frags (72..95), src frags (96..607).
// ---------------------------------------------------------------------------
__global__ __launch_bounds__(256) void k_prep(
    const float* __restrict__ w11, const float* __restrict__ w12,
    const float* __restrict__ w21, const float* __restrict__ w22,
    const float* __restrict__ ema, const float* __restrict__ qkvw,
    const float* __restrict__ src,
    unsigned short* __restrict__ wf, unsigned short* __restrict__ ef,
    unsigned short* __restrict__ wqh, unsigned short* __restrict__ wql,
    unsigned short* __restrict__ sfh, unsigned short* __restrict__ sfl) {
  if (blockIdx.x >= 96) {
    const int bn = blockIdx.x - 96;
    const int tid = threadIdx.x;
    #pragma unroll
    for (int it=0; it<8; ++it) {
      int uidx = it*256 + tid;          // 0..2047
      int half = uidx >> 10;
      int tile = (uidx >> 6) & 15;
      int u    = uidx & 63;
      int rq = tile >> 2, s = tile & 3;
      int g2 = u >> 4, r15 = u & 15;
      int r  = half*64 + rq*16 + r15;   // 0..127
      const float* sp = &src[((size_t)bn*128 + r)*128 + s*32 + g2*4];
      float4 v0 = *(const float4*)sp;
      float4 v1 = *(const float4*)(sp + 16);
      float vv[8] = {v0.x,v0.y,v0.z,v0.w,v1.x,v1.y,v1.z,v1.w};
      unsigned short hh[8], ll[8];
      #pragma unroll
      for (int j=0;j<8;++j) {
        hh[j] = f2bf(vv[j]);
        ll[j] = f2bf(vv[j] - bf2f(hh[j]));
      }
      size_t off = (size_t)bn*16384 + (size_t)uidx*8;
      *(uint4*)(sfh + off) = *(uint4*)hh;
      *(uint4*)(sfl + off) = *(uint4*)ll;
    }
    return;
  }
  if (blockIdx.x >= 72) {
    int tid3 = (blockIdx.x - 72)*256 + threadIdx.x;   // 0..6143
    int s = tid3 / 1536;
    int rem = tid3 - s*1536;
    int n = rem >> 2, g = rem & 3;
    size_t fi = (size_t)((s*384 + n)*4 + g)*8;
    #pragma unroll
    for (int j=0;j<8;++j) {
      int k = 32*s + 16*(j>>2) + 4*g + (j&3);
      float v = qkvw[(size_t)k*384 + n];
      unsigned short h = f2bf(v);
      wqh[fi+j] = h;
      wql[fi+j] = f2bf(v - bf2f(h));
    }
    return;
  }
  if (blockIdx.x >= 64) {
    int tid2 = (blockIdx.x - 64)*256 + threadIdx.x;   // 0..2047
    int mt = tid2 >> 8, s = (tid2 >> 6) & 3, lane = tid2 & 63;
    int cl = lane & 15, g = lane >> 4;
    unsigned short* dst = ef + (size_t)tid2*8;
    #pragma unroll
    for (int j=0;j<8;++j) {
      int k = 32*s + 16*(j>>2) + 4*g + (j&3);
      dst[j] = f2bf(ema[(size_t)(mt*16 + cl)*128 + k]);
    }
    return;
  }
  int tid = blockIdx.x*256 + threadIdx.x;   // 16384 total
  int m = tid >> 12;
  int idx = tid & 4095;
  const float* w; int N;
  if (m==0)      { w = w11; N = 256; }
  else if (m==1) { w = w12; N = 128; }
  else if (m==2) { w = w21; N = 256; }
  else           { w = w22; N = 128; }
  int g  = idx & 3;
  int sn = idx >> 2;
  int n  = (N==256) ? (sn & 255) : (sn & 127);
  int s  = (N==256) ? (sn >> 8)  : (sn >> 7);
  unsigned short* dst = wf + m*32768 + idx*8;
  #pragma unroll
  for (int j=0; j<8; ++j) {
    int k = s*32 + g*4 + (j&3) + 16*(j>>2);
    dst[j] = f2bf(w[(size_t)k*N + n]);
  }
}

// ---------------------------------------------------------------------------
// K-QA: fused QKV projection + per-(bn,h) attention (round-18 structure).
// ---------------------------------------------------------------------------
__global__ __launch_bounds__(256, 5) void k_qa(
    const unsigned short* __restrict__ sfh, const unsigned short* __restrict__ sfl,
    const unsigned short* __restrict__ wqh, const unsigned short* __restrict__ wql,
    const float* __restrict__ qbias, const unsigned short* __restrict__ ef,
    unsigned short* __restrict__ o1b, unsigned short* __restrict__ o2b,
    float* __restrict__ p12) {
  __shared__ __align__(16) unsigned short QFh[2048], QFl[2048];
  __shared__ __align__(16) unsigned short KFh[2048], KFl[2048];
  __shared__ __align__(16) unsigned short VF[2048];
  __shared__ __align__(16) unsigned short eqL[2560], ekL[2560];  // stride 20
  __shared__ __align__(16) float s2L[16*16];
  __shared__ float partp[128];

  const int tid = threadIdx.x;
  const int lane = tid & 63, w = tid >> 6;
  const int cl = lane & 15, g = lane >> 4;
  const int bid = blockIdx.x;
  const int bn = (bid & 7)*64 + (bid >> 6);
  const int h  = (bid >> 3) & 7;
  const int h1 = h >> 1, hb = h & 1;

  if (tid < 128) partp[tid] = 0.f;

  // ---- Phase 0: QKV projection, s-outer / half-inner, batched loads ----
  const float bq = qbias[h*16 + cl];
  const float bk = qbias[128 + h*16 + cl];
  const float bv = qbias[256 + h*16 + cl];
  const unsigned short* gh = sfh + (size_t)bn*16384;
  const unsigned short* gl = sfl + (size_t)bn*16384;
  {
    f32x4 acc[2][3];
    #pragma unroll
    for (int hf=0; hf<2; ++hf)
      #pragma unroll
      for (int nt=0; nt<3; ++nt) acc[hf][nt] = 0;

    #pragma unroll
    for (int s=0; s<4; ++s) {
      bf16x8 bh[3], bl[3];
      #pragma unroll
      for (int nt=0; nt<3; ++nt) {
        int n = nt*128 + h*16 + cl;
        size_t fi = (size_t)((s*384 + n)*4 + g)*8;
        bh[nt] = *(const bf16x8*)(wqh + fi);
        bl[nt] = *(const bf16x8*)(wql + fi);
      }
      size_t a0 = (size_t)((w*4+s)*512 + lane*8);
      bf16x8 ah0 = *(const bf16x8*)&gh[a0];
      bf16x8 al0 = *(const bf16x8*)&gl[a0];
      bf16x8 ah1 = *(const bf16x8*)&gh[a0 + 8192];
      bf16x8 al1 = *(const bf16x8*)&gl[a0 + 8192];
      #pragma unroll
      for (int nt=0; nt<3; ++nt) {
        acc[0][nt] = __builtin_amdgcn_mfma_f32_16x16x32_bf16(ah0, bh[nt], acc[0][nt], 0,0,0);
        acc[0][nt] = __builtin_amdgcn_mfma_f32_16x16x32_bf16(ah0, bl[nt], acc[0][nt], 0,0,0);
        acc[0][nt] = __builtin_amdgcn_mfma_f32_16x16x32_bf16(al0, bh[nt], acc[0][nt], 0,0,0);
        acc[1][nt] = __builtin_amdgcn_mfma_f32_16x16x32_bf16(ah1, bh[nt], acc[1][nt], 0,0,0);
        acc[1][nt] = __builtin_amdgcn_mfma_f32_16x16x32_bf16(ah1, bl[nt], acc[1][nt], 0,0,0);
        acc[1][nt] = __builtin_amdgcn_mfma_f32_16x16x32_bf16(al1, bh[nt], acc[1][nt], 0,0,0);
      }
    }
    #pragma unroll
    for (int hf=0; hf<2; ++hf) {
      const int tb = hf*64 + w*16 + g*4;
      #pragma unroll
      for (int r=0; r<4; ++r) {
        int t = tb + r;
        int s_t = t >> 5, kk = t & 31;
        int g2 = (kk >> 2) & 3, j = ((kk >> 4) << 2) | (kk & 3);
        int fi = s_t*512 + (g2*16 + cl)*8 + j;
        float qv = acc[hf][0][r] + bq;
        unsigned short qh = f2bf(qv);
        QFh[fi] = qh; QFl[fi] = f2bf(qv - bf2f(qh));
        float kv = acc[hf][1][r] + bk;
        unsigned short kh = f2bf(kv);
        KFh[fi] = kh; KFl[fi] = f2bf(kv - bf2f(kh));
        VF[fi] = f2bf(acc[hf][2][r] + bv);
      }
    }
  }
  __syncthreads();   // all fragments visible

  // ---- Phase 1: eq = E@Q, ek = E@K; wave 3 also s_hid + softmax ----
  {
    f32x4 aq[2], ak[2];
    #pragma unroll
    for (int m=0;m<2;++m){ aq[m]=0; ak[m]=0; }
    #pragma unroll
    for (int s=0;s<4;++s) {
      bf16x8 qf = *(const bf16x8*)&QFh[s*512 + lane*8];
      bf16x8 kf = *(const bf16x8*)&KFh[s*512 + lane*8];
      #pragma unroll
      for (int m=0;m<2;++m) {
        int mt = w*2 + m;
        bf16x8 eA = *(const bf16x8*)&ef[(size_t)((mt*4 + s)*64 + lane)*8];
        aq[m] = __builtin_amdgcn_mfma_f32_16x16x32_bf16(eA, qf, aq[m], 0,0,0);
        ak[m] = __builtin_amdgcn_mfma_f32_16x16x32_bf16(eA, kf, ak[m], 0,0,0);
      }
    }
    #pragma unroll
    for (int m=0;m<2;++m)
      #pragma unroll
      for (int r=0;r<4;++r) {
        int row = w*32 + m*16 + g*4 + r;
        eqL[row*20 + cl] = f2bf(aq[m][r]);
        ekL[row*20 + cl] = f2bf(ak[m][r]);
      }
  }
  if (w == 3) {
    f32x4 a2; a2 = 0;
    #pragma unroll
    for (int s=0;s<4;++s) {
      bf16x8 qh = *(const bf16x8*)&QFh[s*512 + lane*8];
      bf16x8 ql = *(const bf16x8*)&QFl[s*512 + lane*8];
      bf16x8 kh = *(const bf16x8*)&KFh[s*512 + lane*8];
      bf16x8 kl = *(const bf16x8*)&KFl[s*512 + lane*8];
      a2 = __builtin_amdgcn_mfma_f32_16x16x32_bf16(qh, kh, a2, 0,0,0);
      a2 = __builtin_amdgcn_mfma_f32_16x16x32_bf16(qh, kl, a2, 0,0,0);
      a2 = __builtin_amdgcn_mfma_f32_16x16x32_bf16(ql, kh, a2, 0,0,0);
    }
    const float CH = 11.313708498984761f * 1.4426950408889634f;
    #pragma unroll
    for (int r=0;r<4;++r) {
      float sv = a2[r];
      float mx = sv;
      mx = fmaxf(mx, __shfl_xor(mx, 1));
      mx = fmaxf(mx, __shfl_xor(mx, 2));
      mx = fmaxf(mx, __shfl_xor(mx, 4));
      mx = fmaxf(mx, __shfl_xor(mx, 8));
      float p = exp2f(fmaf(sv, CH, -mx*CH));
      float sum = p;
      sum += __shfl_xor(sum, 1);
      sum += __shfl_xor(sum, 2);
      sum += __shfl_xor(sum, 4);
      sum += __shfl_xor(sum, 8);
      s2L[(g*4 + r)*16 + cl] = p / sum;
    }
  }
  __syncthreads();

  // ---- Phase 2: token attention (S^T = ek@eq^T, exp2 softmax, deferred inv) ----
  {
    f32x4 accS[8][2];
    #pragma unroll
    for (int kt=0;kt<8;++kt)
      #pragma unroll
      for (int qt=0;qt<2;++qt) accS[kt][qt] = 0;
    U8 eb[2];
    #pragma unroll
    for (int qt=0;qt<2;++qt) {
      eb[qt].d[0] = *(const uint2*)&eqL[(w*32 + qt*16 + cl)*20 + 4*g];
      eb[qt].d[1] = make_uint2(0,0);
    }
    #pragma unroll
    for (int kt=0;kt<8;++kt) {
      U8 ea;
      ea.d[0] = *(const uint2*)&ekL[(kt*16 + cl)*20 + 4*g];
      ea.d[1] = make_uint2(0,0);
      #pragma unroll
      for (int qt=0;qt<2;++qt)
        accS[kt][qt] = __builtin_amdgcn_mfma_f32_16x16x32_bf16(ea.v, eb[qt].v, accS[kt][qt], 0,0,0);
    }
    bf16x8 vfr[4];
    #pragma unroll
    for (int s=0;s<4;++s) vfr[s] = *(const bf16x8*)&VF[s*512 + lane*8];
    const float CE = 4.0f * 1.4426950408889634f;
    #pragma unroll
    for (int qt=0;qt<2;++qt) {
      float mx = -1e30f;
      #pragma unroll
      for (int kt=0;kt<8;++kt)
        #pragma unroll
        for (int r=0;r<4;++r)
          mx = fmaxf(mx, accS[kt][qt][r]);
      mx = fmaxf(mx, __shfl_xor(mx, 16));
      mx = fmaxf(mx, __shfl_xor(mx, 32));
      float mxc = mx * CE;
      float sum = 0.f;
      #pragma unroll
      for (int kt=0;kt<8;++kt)
        #pragma unroll
        for (int r=0;r<4;++r) {
          float p = exp2f(fmaf(accS[kt][qt][r], CE, -mxc));
          accS[kt][qt][r] = p; sum += p;
        }
      sum += __shfl_xor(sum, 16);
      sum += __shfl_xor(sum, 32);
      float invq = 1.0f / sum;      // for q-col = cl
      f32x4 o; o = 0;
      #pragma unroll
      for (int s=0;s<4;++s) {
        U8 pa;
        #pragma unroll
        for (int j=0;j<8;++j)
          pa.u[j] = f2bf(accS[2*s + (j>>2)][qt][j&3]);
        o = __builtin_amdgcn_mfma_f32_16x16x32_bf16(pa.v, vfr[s], o, 0,0,0);
      }
      float ov[4];
      #pragma unroll
      for (int r=0;r<4;++r) {
        float invr = __shfl(invq, g*4 + r);   // lane g*4+r holds inv for that q-row
        ov[r] = o[r] * invr;
        int e = w*32 + qt*16 + g*4 + r;
        int t2 = hb*64 + (e>>1), cb = (e&1)*64 + h1*16 + cl;
        o1b[((size_t)(bn*128 + t2))*128 + cb] = f2bf(ov[r]);
      }
      float s0 = ov[0]+ov[2], q0 = ov[0]*ov[0]+ov[2]*ov[2];
      float s1 = ov[1]+ov[3], q1 = ov[1]*ov[1]+ov[3]*ov[3];
      s0 += __shfl_xor(s0,16); s0 += __shfl_xor(s0,32);
      q0 += __shfl_xor(q0,16); q0 += __shfl_xor(q0,32);
      s1 += __shfl_xor(s1,16); s1 += __shfl_xor(s1,32);
      q1 += __shfl_xor(q1,16); q1 += __shfl_xor(q1,32);
      if (g == 0) {
        atomicAdd(&partp[cl],      s0);
        atomicAdd(&partp[16+cl],   q0);
        atomicAdd(&partp[32+cl],   s1);
        atomicAdd(&partp[48+cl],   q1);
      }
    }
  }

  // ---- Phase 3: O2 = V @ A2^T (V A-frag derived from VF) ----
  {
    U8 bb;
    #pragma unroll
    for (int j=0;j<4;++j) bb.u[j] = f2bf(s2L[cl*16 + 4*g + j]);
    bb.d[1] = make_uint2(0,0);
    #pragma unroll
    for (int m=0;m<2;++m) {
      int tt = w*2 + m;
      int t = tt*16 + cl;
      int s3 = t >> 5;
      int g23 = (t >> 2) & 3;
      int j3 = ((t >> 4) & 1)*4 + (t & 3);
      U8 va;
      #pragma unroll
      for (int jj=0;jj<4;++jj)
        va.u[jj] = VF[s3*512 + (g23*16 + 4*g + jj)*8 + j3];
      va.d[1] = make_uint2(0,0);
      f32x4 o; o = 0;
      o = __builtin_amdgcn_mfma_f32_16x16x32_bf16(va.v, bb.v, o, 0,0,0);
      #pragma unroll
      for (int r=0;r<4;++r) {
        int tr = tt*16 + g*4 + r;
        int t2 = hb*64 + (tr>>1), cb = (tr&1)*64 + h1*16 + cl;
        o2b[((size_t)(bn*128 + t2))*128 + cb] = f2bf(o[r]);
      }
      float s0 = o[0]+o[2], q0 = o[0]*o[0]+o[2]*o[2];
      float s1 = o[1]+o[3], q1 = o[1]*o[1]+o[3]*o[3];
      s0 += __shfl_xor(s0,16); s0 += __shfl_xor(s0,32);
      q0 += __shfl_xor(q0,16); q0 += __shfl_xor(q0,32);
      s1 += __shfl_xor(s1,16); s1 += __shfl_xor(s1,32);
      q1 += __shfl_xor(q1,16); q1 += __shfl_xor(q1,32);
      if (g == 0) {
        atomicAdd(&partp[64+cl],    s0);
        atomicAdd(&partp[64+16+cl], q0);
        atomicAdd(&partp[64+32+cl], s1);
        atomicAdd(&partp[64+48+cl], q1);
      }
    }
  }
  __syncthreads();
  if (tid < 128) p12[(size_t)(bn*8 + h)*128 + tid] = partp[tid];
}

// ---------------------------------------------------------------------------
// K-red12: tree-reduce p12[4096][128] -> q12[128][128]
// ---------------------------------------------------------------------------
__global__ __launch_bounds__(256) void k_red12(
    const float* __restrict__ p12, float* __restrict__ q12) {
  __shared__ float red[256];
  const int tid = threadIdx.x;
  const int slot = tid & 127, half = tid >> 7;
  const int h = blockIdx.x & 7, chunk = blockIdx.x >> 3;
  float s = 0.f;
  for (int t = half; t < 32; t += 2)
    s += p12[(size_t)((chunk*32 + t)*8 + h)*128 + slot];
  red[tid] = s;
  __syncthreads();
  if (tid < 128)
    q12[(size_t)blockIdx.x*128 + tid] = red[tid] + red[tid + 128];
}

// K4: finalize bn1/bn2 from q12 (64KB, L2-resident)
__global__ __launch_bounds__(256) void k_fin12(
    const float* __restrict__ q12,
    const float* __restrict__ g1, const float* __restrict__ b1,
    const float* __restrict__ g2, const float* __restrict__ b2,
    float* __restrict__ stats) {
  const int tid = threadIdx.x;       // 0..255
  const int br = tid >> 7, c = tid & 127;
  const int grp = c >> 6, h1 = (c & 63) >> 4, cl = c & 15;
  const int slot = br*64 + grp*32 + cl;
  float s = 0.f, q = 0.f;
  #pragma unroll 4
  for (int chunk = 0; chunk < 16; ++chunk) {
    const float* p0 = &q12[(size_t)(chunk*8 + h1*2)*128];
    s += p0[slot]      + p0[128 + slot];
    q += p0[slot + 16] + p0[128 + slot + 16];
  }
  const float inv = 1.0f/65536.0f;
  float m = s*inv, v = q*inv - m*m;
  float r = rsqrtf(v + 1e-5f);
  float gv = br ? g2[c] : g1[c];
  float bv = br ? b2[c] : b1[c];
  float sc = r * gv;
  stats[br*256 + c]       = sc;
  stats[br*256 + 128 + c] = bv - m*sc;
}

// ---------------------------------------------------------------------------
// K5: fused dual FFN, bf16 MFMA. Writes bf16 pre-bn3 (outb) + p3 partials
// computed on the ROUNDED values. __launch_bounds__(512,2): 2-block floor ->
// 128-VGPR budget; (512,4) silently capped VGPR at 64 and spilled ~46MB.
// ---------------------------------------------------------------------------
__global__ __launch_bounds__(512, 2) void k_ff(
    const unsigned short* __restrict__ o1b, const unsigned short* __restrict__ o2b,
    const float* __restrict__ src,
    const float* __restrict__ bb11, const float* __restrict__ bb12,
    const float* __restrict__ bb21, const float* __restrict__ bb22,
    const unsigned short* __restrict__ wf,
    const float* __restrict__ stats, unsigned short* __restrict__ outb,
    float* __restrict__ p3) {
  __shared__ __align__(16) unsigned short Xbf[64*128];  // 16 KB
  __shared__ __align__(16) unsigned short Hbf[64*128];  // 16 KB
  const int tid = threadIdx.x;
  const int lane = tid & 63, w = tid >> 6;          // w = 0..7
  const int cl = lane & 15, g = lane >> 4;
  const size_t rb = (size_t)blockIdx.x * 64;

  f32x4 acc2[4];
  #pragma unroll
  for (int m=0;m<4;++m) acc2[m] = 0;

  for (int br=0; br<2; ++br) {
    const unsigned short* xin = br ? o2b : o1b;
    const float* sc_ = stats + br*256;
    const float* sh_ = sc_ + 128;
    const unsigned short* w1f = wf + br*65536;
    const unsigned short* w2f = w1f + 32768;
    const float* b1g = br ? bb21 : bb11;

    __syncthreads();
    #pragma unroll
    for (int it=0; it<4; ++it) {
      int idx = it*512 + tid;
      int row = idx >> 5, c4 = (idx & 31)*4;
      uint2 u = *(const uint2*)&xin[(rb+row)*128 + c4];
      float x0 = bf2f((unsigned short)(u.x & 0xffff));
      float x1 = bf2f((unsigned short)(u.x >> 16));
      float x2 = bf2f((unsigned short)(u.y & 0xffff));
      float x3 = bf2f((unsigned short)(u.y >> 16));
      unsigned int lo = f2bf(fmaf(x0, sc_[c4+0], sh_[c4+0]))
                      | ((unsigned int)f2bf(fmaf(x1, sc_[c4+1], sh_[c4+1])) << 16);
      unsigned int hi = f2bf(fmaf(x2, sc_[c4+2], sh_[c4+2]))
                      | ((unsigned int)f2bf(fmaf(x3, sc_[c4+3], sh_[c4+3])) << 16);
      unsigned int byteo = (unsigned)((row*256 + c4*2) ^ ((row&7)<<4));
      *(uint2*)((char*)Xbf + byteo) = make_uint2(lo, hi);
    }
    __syncthreads();

    #pragma unroll
    for (int hc=0; hc<2; ++hc) {
      f32x4 acc1[4];
      #pragma unroll
      for (int m=0;m<4;++m) acc1[m] = 0;

      bf16x8 bfs[4];
      #pragma unroll
      for (int s=0; s<4; ++s) {
        int n = hc*128 + w*16 + cl;
        bfs[s] = *(const bf16x8*)(w1f + (size_t)((s*256 + n)*4 + g)*8);
      }
      #pragma unroll
      for (int s=0; s<4; ++s) {
        #pragma unroll
        for (int m=0; m<4; ++m) {
          int row = m*16 + cl;
          U8 u;
          u.d[0] = *(uint2*)((char*)Xbf + (unsigned)((row*256 + (s*32 + g*4)*2)    ^ ((row&7)<<4)));
          u.d[1] = *(uint2*)((char*)Xbf + (unsigned)((row*256 + (s*32 +16+ g*4)*2) ^ ((row&7)<<4)));
          acc1[m] = __builtin_amdgcn_mfma_f32_16x16x32_bf16(u.v, bfs[s], acc1[m], 0, 0, 0);
        }
      }

      {
        int col = w*16 + cl;
        float bias = b1g[hc*128 + col];
        #pragma unroll
        for (int m=0; m<4; ++m) {
          #pragma unroll
          for (int r=0; r<4; ++r) {
            float y = gelu_f(acc1[m][r] + bias);
            int row = m*16 + g*4 + r;
            unsigned int byteo = (unsigned)((row*256 + col*2) ^ ((row&7)<<4));
            *(unsigned short*)((char*)Hbf + byteo) = f2bf(y);
          }
        }
      }
      __syncthreads();

      bf16x8 bf2[4];
      #pragma unroll
      for (int s2l=0; s2l<4; ++s2l) {
        int s2 = hc*4 + s2l;
        int n = w*16 + cl;
        bf2[s2l] = *(const bf16x8*)(w2f + (size_t)((s2*128 + n)*4 + g)*8);
      }
      #pragma unroll
      for (int s2l=0; s2l<4; ++s2l) {
        #pragma unroll
        for (int m=0; m<4; ++m) {
          int row = m*16 + cl;
          U8 u;
          u.d[0] = *(uint2*)((char*)Hbf + (unsigned)((row*256 + (s2l*32 + g*4)*2)    ^ ((row&7)<<4)));
          u.d[1] = *(uint2*)((char*)Hbf + (unsigned)((row*256 + (s2l*32 +16+ g*4)*2) ^ ((row&7)<<4)));
          acc2[m] = __builtin_amdgcn_mfma_f32_16x16x32_bf16(u.v, bf2[s2l], acc2[m], 0, 0, 0);
        }
      }
      __syncthreads();
    }
  }

  {
    int col = w*16 + cl;
    float bias = bb12[col] + bb22[col];
    float cs = 0.f, cq = 0.f;
    #pragma unroll
    for (int m=0; m<4; ++m) {
      #pragma unroll
      for (int r=0; r<4; ++r) {
        size_t row = rb + m*16 + g*4 + r;
        float o = src[row*128 + col] + acc2[m][r] + bias;
        unsigned short ob = f2bf(o);
        outb[row*128 + col] = ob;
        float orv = bf2f(ob);           // stats on rounded value
        cs += orv; cq = fmaf(orv, orv, cq);
      }
    }
    cs += __shfl_down(cs, 32); cs += __shfl_down(cs, 16);
    cq += __shfl_down(cq, 32); cq += __shfl_down(cq, 16);
    if (g == 0) {
      p3[(size_t)blockIdx.x*256 + col]       = cs;
      p3[(size_t)blockIdx.x*256 + 128 + col] = cq;
    }
  }
}

// K-red3: tree-reduce p3[1024][256] -> q3[32][256]
__global__ __launch_bounds__(256) void k_red3(
    const float* __restrict__ p3, float* __restrict__ q3) {
  const int tid = threadIdx.x;
  float s = 0.f;
  const int b0 = blockIdx.x*32;
  for (int b = b0; b < b0 + 32; ++b)
    s += p3[(size_t)b*256 + tid];
  q3[(size_t)blockIdx.x*256 + tid] = s;
}

// K6: finalize bn3 from q3 (32KB)
__global__ __launch_bounds__(256) void k_fin3(
    const float* __restrict__ q3, const float* __restrict__ g3,
    const float* __restrict__ b3, float* __restrict__ stats) {
  __shared__ float acc[256];
  const int tid = threadIdx.x;
  float s = 0.f;
  #pragma unroll 4
  for (int i = 0; i < 32; ++i) s += q3[i*256 + tid];
  acc[tid] = s;
  __syncthreads();
  if (tid < 128) {
    const float inv = 1.0f/65536.0f;
    float m = acc[tid]*inv, v = acc[128+tid]*inv - m*m;
    float r = rsqrtf(v + 1e-5f);
    float scv = r*g3[tid];
    stats[512 + tid] = scv;
    stats[640 + tid] = b3[tid] - m*scv;
  }
}

// K7: final batchnorm: bf16 pre-bn3 in, fp32 d_out out.
// 1048576 uint4-units total; 524288 threads x 2 iters.
__global__ __launch_bounds__(256) void k_bn3(
    const unsigned short* __restrict__ outb, const float* __restrict__ stats,
    float* __restrict__ outp) {
  const int i0 = blockIdx.x*256 + threadIdx.x;   // uint4 index (8 bf16)
  const int c0 = (i0 & 15) * 8;                  // channel base (524288%16==0)
  #pragma unroll
  for (int it=0; it<2; ++it) {
    size_t ui = (size_t)i0 + (size_t)it*524288;
    size_t eb = ui * 8;
    uint4 u = *(const uint4*)&outb[eb];
    unsigned int uu[4] = {u.x, u.y, u.z, u.w};
    float out[8];
    #pragma unroll
    for (int p=0; p<4; ++p) {
      float a = bf2f((unsigned short)(uu[p] & 0xffff));
      float b = bf2f((unsigned short)(uu[p] >> 16));
      out[p*2]   = fmaf(a, stats[512 + c0 + p*2],     stats[640 + c0 + p*2]);
      out[p*2+1] = fmaf(b, stats[512 + c0 + p*2 + 1], stats[640 + c0 + p*2 + 1]);
    }
    *(float4*)&outp[eb]     = make_float4(out[0], out[1], out[2], out[3]);
    *(float4*)&outp[eb + 4] = make_float4(out[4], out[5], out[6], out[7]);
  }
}

extern "C" void kernel_launch(void* const* d_in, const int* in_sizes, int n_in,
                              void* d_out, int out_size, void* d_ws, size_t ws_size,
                              hipStream_t stream) {
  const float* src   = (const float*)d_in[0];
  const float* qkv_w = (const float*)d_in[1];
  const float* qkv_b = (const float*)d_in[2];
  const float* ff1w1 = (const float*)d_in[3];
  const float* ff1b1 = (const float*)d_in[4];
  const float* ff1w2 = (const float*)d_in[5];
  const float* ff1b2 = (const float*)d_in[6];
  const float* ff2w1 = (const float*)d_in[7];
  const float* ff2b1 = (const float*)d_in[8];
  const float* ff2w2 = (const float*)d_in[9];
  const float* ff2b2 = (const float*)d_in[10];
  const float* g1 = (const float*)d_in[11];
  const float* b1 = (const float*)d_in[12];
  const float* g2 = (const float*)d_in[13];
  const float* b2 = (const float*)d_in[14];
  const float* g3 = (const float*)d_in[15];
  const float* b3 = (const float*)d_in[16];
  const float* ema = (const float*)d_in[17];

  float* ws = (float*)d_ws;
  unsigned short* o1b = (unsigned short*)ws;               // 8388608 bf16
  unsigned short* o2b = o1b + 8388608;
  float* p12 = (float*)(o2b + 8388608);  // 4096*128
  float* p3  = p12 + 524288;             // 1024*256
  float* stats = p3 + 262144;            // 768 (+pad)
  unsigned short* wfrag = (unsigned short*)(stats + 1024);  // 4*32768 bf16
  unsigned short* efrag = wfrag + 131072;                   // 16384 bf16
  unsigned short* wqh   = efrag + 16384;                    // 49152 bf16
  unsigned short* wql   = wqh + 49152;                      // 49152 bf16
  float* q12 = (float*)(wql + 49152);    // 128*128
  float* q3  = q12 + 16384;              // 32*256
  unsigned short* sfh = (unsigned short*)(q3 + 8192);       // 512*16384 bf16
  unsigned short* sfl = sfh + 8388608;
  unsigned short* outbb = sfl + 8388608;                    // 8388608 bf16
  float* outp = (float*)d_out;

  k_prep<<<dim3(608), dim3(256), 0, stream>>>(ff1w1, ff1w2, ff2w1, ff2w2, ema,
                                              qkv_w, src, wfrag, efrag,
                                              wqh, wql, sfh, sfl);
  k_qa<<<dim3(4096), dim3(256), 0, stream>>>(sfh, sfl, wqh, wql, qkv_b, efrag,
                                             o1b, o2b, p12);
  k_red12<<<dim3(128), dim3(256), 0, stream>>>(p12, q12);
  k_fin12<<<dim3(1), dim3(256), 0, stream>>>(q12, g1, b1, g2, b2, stats);
  k_ff<<<dim3(1024), dim3(512), 0, stream>>>(o1b, o2b, src,
      ff1b1, ff1b2, ff2b1, ff2b2, wfrag, stats, outbb, p3);
  k_red3<<<dim3(32), dim3(256), 0, stream>>>(p3, q3);
  k_fin3<<<dim3(1), dim3(256), 0, stream>>>(q3, g3, b3, stats);
  k_bn3<<<dim3(2048), dim3(256), 0, stream>>>(outbb, stats, outp);
}

// Round 24
// 179.649 us; speedup vs baseline: 1.0010x; 1.0010x over previous
//
#include <hip/hip_runtime.h>
#include <math.h>

// Problem constants
#define BN_ 512     // B*NVARS
#define T_  128
#define C_  128
#define H_  8
#define D_  16
#define F_  256
#define M_  65536   // BN_*T_

typedef __bf16 bf16x8 __attribute__((ext_vector_type(8)));
typedef float f32x4 __attribute__((ext_vector_type(4)));
union U8 { uint2 d[2]; bf16x8 v; unsigned short u[8]; };

// native f32->bf16 (RNE) -- lets compiler emit v_cvt_pk_bf16_f32
__device__ inline unsigned short f2bf(float x) {
  union { __bf16 b; unsigned short u; } c;
  c.b = (__bf16)x;
  return c.u;
}
__device__ inline float bf2f(unsigned short h) {
  return __uint_as_float((unsigned int)h << 16);
}
// exact-enough GELU: erf via A&S 7.1.26, |eps|<=1.5e-7
__device__ inline float gelu_f(float x) {
  float z  = x * 0.70710678118654752f;
  float az = fabsf(z);
  float t  = 1.0f / (1.0f + 0.3275911f * az);
  float poly = ((((1.061405429f*t - 1.453152027f)*t + 1.421413741f)*t
                 - 0.284496736f)*t + 0.254829592f)*t;
  float e  = __expf(-z*z);
  float er = 1.0f - poly*e;
  er = (z < 0.0f) ? -er : er;
  return 0.5f * x * (1.0f + er);
}

// ---------------------------------------------------------------------------
// K-prep: FFN weight frags (blocks 0..63), E frags (64..71),
//         qkv_w split hi/lo frags (72..95), src frags (96..607).
// ---------------------------------------------------------------------------
__global__ __launch_bounds__(256) void k_prep(
    const float* __restrict__ w11, const float* __restrict__ w12,
    const float* __restrict__ w21, const float* __restrict__ w22,
    const float* __restrict__ ema, const float* __restrict__ qkvw,
    const float* __restrict__ src,
    unsigned short* __restrict__ wf, unsigned short* __restrict__ ef,
    unsigned short* __restrict__ wqh, unsigned short* __restrict__ wql,
    unsigned short* __restrict__ sfh, unsigned short* __restrict__ sfl) {
  if (blockIdx.x >= 96) {
    const int bn = blockIdx.x - 96;
    const int tid = threadIdx.x;
    #pragma unroll
    for (int it=0; it<8; ++it) {
      int uidx = it*256 + tid;          // 0..2047
      int half = uidx >> 10;
      int tile = (uidx >> 6) & 15;
      int u    = uidx & 63;
      int rq = tile >> 2, s = tile & 3;
      int g2 = u >> 4, r15 = u & 15;
      int r  = half*64 + rq*16 + r15;   // 0..127
      const float* sp = &src[((size_t)bn*128 + r)*128 + s*32 + g2*4];
      float4 v0 = *(const float4*)sp;
      float4 v1 = *(const float4*)(sp + 16);
      float vv[8] = {v0.x,v0.y,v0.z,v0.w,v1.x,v1.y,v1.z,v1.w};
      unsigned short hh[8], ll[8];
      #pragma unroll
      for (int j=0;j<8;++j) {
        hh[j] = f2bf(vv[j]);
        ll[j] = f2bf(vv[j] - bf2f(hh[j]));
      }
      size_t off = (size_t)bn*16384 + (size_t)uidx*8;
      *(uint4*)(sfh + off) = *(uint4*)hh;
      *(uint4*)(sfl + off) = *(uint4*)ll;
    }
    return;
  }
  if (blockIdx.x >= 72) {
    int tid3 = (blockIdx.x - 72)*256 + threadIdx.x;   // 0..6143
    int s = tid3 / 1536;
    int rem = tid3 - s*1536;
    int n = rem >> 2, g = rem & 3;
    size_t fi = (size_t)((s*384 + n)*4 + g)*8;
    #pragma unroll
    for (int j=0;j<8;++j) {
      int k = 32*s + 16*(j>>2) + 4*g + (j&3);
      float v = qkvw[(size_t)k*384 + n];
      unsigned short h = f2bf(v);
      wqh[fi+j] = h;
      wql[fi+j] = f2bf(v - bf2f(h));
    }
    return;
  }
  if (blockIdx.x >= 64) {
    int tid2 = (blockIdx.x - 64)*256 + threadIdx.x;   // 0..2047
    int mt = tid2 >> 8, s = (tid2 >> 6) & 3, lane = tid2 & 63;
    int cl = lane & 15, g = lane >> 4;
    unsigned short* dst = ef + (size_t)tid2*8;
    #pragma unroll
    for (int j=0;j<8;++j) {
      int k = 32*s + 16*(j>>2) + 4*g + (j&3);
      dst[j] = f2bf(ema[(size_t)(mt*16 + cl)*128 + k]);
    }
    return;
  }
  int tid = blockIdx.x*256 + threadIdx.x;   // 16384 total
  int m = tid >> 12;
  int idx = tid & 4095;
  const float* w; int N;
  if (m==0)      { w = w11; N = 256; }
  else if (m==1) { w = w12; N = 128; }
  else if (m==2) { w = w21; N = 256; }
  else           { w = w22; N = 128; }
  int g  = idx & 3;
  int sn = idx >> 2;
  int n  = (N==256) ? (sn & 255) : (sn & 127);
  int s  = (N==256) ? (sn >> 8)  : (sn >> 7);
  unsigned short* dst = wf + m*32768 + idx*8;
  #pragma unroll
  for (int j=0; j<8; ++j) {
    int k = s*32 + g*4 + (j&3) + 16*(j>>2);
    dst[j] = f2bf(w[(size_t)k*N + n]);
  }
}

// ---------------------------------------------------------------------------
// K-QA: fused QKV projection + per-(bn,h) attention (round-18 structure).
// ---------------------------------------------------------------------------
__global__ __launch_bounds__(256, 5) void k_qa(
    const unsigned short* __restrict__ sfh, const unsigned short* __restrict__ sfl,
    const unsigned short* __restrict__ wqh, const unsigned short* __restrict__ wql,
    const float* __restrict__ qbias, const unsigned short* __restrict__ ef,
    unsigned short* __restrict__ o1b, unsigned short* __restrict__ o2b,
    float* __restrict__ p12) {
  __shared__ __align__(16) unsigned short QFh[2048], QFl[2048];
  __shared__ __align__(16) unsigned short KFh[2048], KFl[2048];
  __shared__ __align__(16) unsigned short VF[2048];
  __shared__ __align__(16) unsigned short eqL[2560], ekL[2560];  // stride 20
  __shared__ __align__(16) float s2L[16*16];
  __shared__ float partp[128];

  const int tid = threadIdx.x;
  const int lane = tid & 63, w = tid >> 6;
  const int cl = lane & 15, g = lane >> 4;
  const int bid = blockIdx.x;
  const int bn = (bid & 7)*64 + (bid >> 6);
  const int h  = (bid >> 3) & 7;
  const int h1 = h >> 1, hb = h & 1;

  if (tid < 128) partp[tid] = 0.f;

  // ---- Phase 0: QKV projection, s-outer / half-inner, batched loads ----
  const float bq = qbias[h*16 + cl];
  const float bk = qbias[128 + h*16 + cl];
  const float bv = qbias[256 + h*16 + cl];
  const unsigned short* gh = sfh + (size_t)bn*16384;
  const unsigned short* gl = sfl + (size_t)bn*16384;
  {
    f32x4 acc[2][3];
    #pragma unroll
    for (int hf=0; hf<2; ++hf)
      #pragma unroll
      for (int nt=0; nt<3; ++nt) acc[hf][nt] = 0;

    #pragma unroll
    for (int s=0; s<4; ++s) {
      bf16x8 bh[3], bl[3];
      #pragma unroll
      for (int nt=0; nt<3; ++nt) {
        int n = nt*128 + h*16 + cl;
        size_t fi = (size_t)((s*384 + n)*4 + g)*8;
        bh[nt] = *(const bf16x8*)(wqh + fi);
        bl[nt] = *(const bf16x8*)(wql + fi);
      }
      size_t a0 = (size_t)((w*4+s)*512 + lane*8);
      bf16x8 ah0 = *(const bf16x8*)&gh[a0];
      bf16x8 al0 = *(const bf16x8*)&gl[a0];
      bf16x8 ah1 = *(const bf16x8*)&gh[a0 + 8192];
      bf16x8 al1 = *(const bf16x8*)&gl[a0 + 8192];
      #pragma unroll
      for (int nt=0; nt<3; ++nt) {
        acc[0][nt] = __builtin_amdgcn_mfma_f32_16x16x32_bf16(ah0, bh[nt], acc[0][nt], 0,0,0);
        acc[0][nt] = __builtin_amdgcn_mfma_f32_16x16x32_bf16(ah0, bl[nt], acc[0][nt], 0,0,0);
        acc[0][nt] = __builtin_amdgcn_mfma_f32_16x16x32_bf16(al0, bh[nt], acc[0][nt], 0,0,0);
        acc[1][nt] = __builtin_amdgcn_mfma_f32_16x16x32_bf16(ah1, bh[nt], acc[1][nt], 0,0,0);
        acc[1][nt] = __builtin_amdgcn_mfma_f32_16x16x32_bf16(ah1, bl[nt], acc[1][nt], 0,0,0);
        acc[1][nt] = __builtin_amdgcn_mfma_f32_16x16x32_bf16(al1, bh[nt], acc[1][nt], 0,0,0);
      }
    }
    #pragma unroll
    for (int hf=0; hf<2; ++hf) {
      const int tb = hf*64 + w*16 + g*4;
      #pragma unroll
      for (int r=0; r<4; ++r) {
        int t = tb + r;
        int s_t = t >> 5, kk = t & 31;
        int g2 = (kk >> 2) & 3, j = ((kk >> 4) << 2) | (kk & 3);
        int fi = s_t*512 + (g2*16 + cl)*8 + j;
        float qv = acc[hf][0][r] + bq;
        unsigned short qh = f2bf(qv);
        QFh[fi] = qh; QFl[fi] = f2bf(qv - bf2f(qh));
        float kv = acc[hf][1][r] + bk;
        unsigned short kh = f2bf(kv);
        KFh[fi] = kh; KFl[fi] = f2bf(kv - bf2f(kh));
        VF[fi] = f2bf(acc[hf][2][r] + bv);
      }
    }
  }
  __syncthreads();   // all fragments visible

  // ---- Phase 1: eq = E@Q, ek = E@K; wave 3 also s_hid + softmax ----
  {
    f32x4 aq[2], ak[2];
    #pragma unroll
    for (int m=0;m<2;++m){ aq[m]=0; ak[m]=0; }
    #pragma unroll
    for (int s=0;s<4;++s) {
      bf16x8 qf = *(const bf16x8*)&QFh[s*512 + lane*8];
      bf16x8 kf = *(const bf16x8*)&KFh[s*512 + lane*8];
      #pragma unroll
      for (int m=0;m<2;++m) {
        int mt = w*2 + m;
        bf16x8 eA = *(const bf16x8*)&ef[(size_t)((mt*4 + s)*64 + lane)*8];
        aq[m] = __builtin_amdgcn_mfma_f32_16x16x32_bf16(eA, qf, aq[m], 0,0,0);
        ak[m] = __builtin_amdgcn_mfma_f32_16x16x32_bf16(eA, kf, ak[m], 0,0,0);
      }
    }
    #pragma unroll
    for (int m=0;m<2;++m)
      #pragma unroll
      for (int r=0;r<4;++r) {
        int row = w*32 + m*16 + g*4 + r;
        eqL[row*20 + cl] = f2bf(aq[m][r]);
        ekL[row*20 + cl] = f2bf(ak[m][r]);
      }
  }
  if (w == 3) {
    f32x4 a2; a2 = 0;
    #pragma unroll
    for (int s=0;s<4;++s) {
      bf16x8 qh = *(const bf16x8*)&QFh[s*512 + lane*8];
      bf16x8 ql = *(const bf16x8*)&QFl[s*512 + lane*8];
      bf16x8 kh = *(const bf16x8*)&KFh[s*512 + lane*8];
      bf16x8 kl = *(const bf16x8*)&KFl[s*512 + lane*8];
      a2 = __builtin_amdgcn_mfma_f32_16x16x32_bf16(qh, kh, a2, 0,0,0);
      a2 = __builtin_amdgcn_mfma_f32_16x16x32_bf16(qh, kl, a2, 0,0,0);
      a2 = __builtin_amdgcn_mfma_f32_16x16x32_bf16(ql, kh, a2, 0,0,0);
    }
    const float CH = 11.313708498984761f * 1.4426950408889634f;
    #pragma unroll
    for (int r=0;r<4;++r) {
      float sv = a2[r];
      float mx = sv;
      mx = fmaxf(mx, __shfl_xor(mx, 1));
      mx = fmaxf(mx, __shfl_xor(mx, 2));
      mx = fmaxf(mx, __shfl_xor(mx, 4));
      mx = fmaxf(mx, __shfl_xor(mx, 8));
      float p = exp2f(fmaf(sv, CH, -mx*CH));
      float sum = p;
      sum += __shfl_xor(sum, 1);
      sum += __shfl_xor(sum, 2);
      sum += __shfl_xor(sum, 4);
      sum += __shfl_xor(sum, 8);
      s2L[(g*4 + r)*16 + cl] = p / sum;
    }
  }
  __syncthreads();

  // ---- Phase 2: token attention (S^T = ek@eq^T, exp2 softmax, deferred inv) ----
  {
    f32x4 accS[8][2];
    #pragma unroll
    for (int kt=0;kt<8;++kt)
      #pragma unroll
      for (int qt=0;qt<2;++qt) accS[kt][qt] = 0;
    U8 eb[2];
    #pragma unroll
    for (int qt=0;qt<2;++qt) {
      eb[qt].d[0] = *(const uint2*)&eqL[(w*32 + qt*16 + cl)*20 + 4*g];
      eb[qt].d[1] = make_uint2(0,0);
    }
    #pragma unroll
    for (int kt=0;kt<8;++kt) {
      U8 ea;
      ea.d[0] = *(const uint2*)&ekL[(kt*16 + cl)*20 + 4*g];
      ea.d[1] = make_uint2(0,0);
      #pragma unroll
      for (int qt=0;qt<2;++qt)
        accS[kt][qt] = __builtin_amdgcn_mfma_f32_16x16x32_bf16(ea.v, eb[qt].v, accS[kt][qt], 0,0,0);
    }
    bf16x8 vfr[4];
    #pragma unroll
    for (int s=0;s<4;++s) vfr[s] = *(const bf16x8*)&VF[s*512 + lane*8];
    const float CE = 4.0f * 1.4426950408889634f;
    #pragma unroll
    for (int qt=0;qt<2;++qt) {
      float mx = -1e30f;
      #pragma unroll
      for (int kt=0;kt<8;++kt)
        #pragma unroll
        for (int r=0;r<4;++r)
          mx = fmaxf(mx, accS[kt][qt][r]);
      mx = fmaxf(mx, __shfl_xor(mx, 16));
      mx = fmaxf(mx, __shfl_xor(mx, 32));
      float mxc = mx * CE;
      float sum = 0.f;
      #pragma unroll
      for (int kt=0;kt<8;++kt)
        #pragma unroll
        for (int r=0;r<4;++r) {
          float p = exp2f(fmaf(accS[kt][qt][r], CE, -mxc));
          accS[kt][qt][r] = p; sum += p;
        }
      sum += __shfl_xor(sum, 16);
      sum += __shfl_xor(sum, 32);
      float invq = 1.0f / sum;      // for q-col = cl
      f32x4 o; o = 0;
      #pragma unroll
      for (int s=0;s<4;++s) {
        U8 pa;
        #pragma unroll
        for (int j=0;j<8;++j)
          pa.u[j] = f2bf(accS[2*s + (j>>2)][qt][j&3]);
        o = __builtin_amdgcn_mfma_f32_16x16x32_bf16(pa.v, vfr[s], o, 0,0,0);
      }
      float ov[4];
      #pragma unroll
      for (int r=0;r<4;++r) {
        float invr = __shfl(invq, g*4 + r);   // lane g*4+r holds inv for that q-row
        ov[r] = o[r] * invr;
        int e = w*32 + qt*16 + g*4 + r;
        int t2 = hb*64 + (e>>1), cb = (e&1)*64 + h1*16 + cl;
        o1b[((size_t)(bn*128 + t2))*128 + cb] = f2bf(ov[r]);
      }
      float s0 = ov[0]+ov[2], q0 = ov[0]*ov[0]+ov[2]*ov[2];
      float s1 = ov[1]+ov[3], q1 = ov[1]*ov[1]+ov[3]*ov[3];
      s0 += __shfl_xor(s0,16); s0 += __shfl_xor(s0,32);
      q0 += __shfl_xor(q0,16); q0 += __shfl_xor(q0,32);
      s1 += __shfl_xor(s1,16); s1 += __shfl_xor(s1,32);
      q1 += __shfl_xor(q1,16); q1 += __shfl_xor(q1,32);
      if (g == 0) {
        atomicAdd(&partp[cl],      s0);
        atomicAdd(&partp[16+cl],   q0);
        atomicAdd(&partp[32+cl],   s1);
        atomicAdd(&partp[48+cl],   q1);
      }
    }
  }

  // ---- Phase 3: O2 = V @ A2^T (V A-frag derived from VF) ----
  {
    U8 bb;
    #pragma unroll
    for (int j=0;j<4;++j) bb.u[j] = f2bf(s2L[cl*16 + 4*g + j]);
    bb.d[1] = make_uint2(0,0);
    #pragma unroll
    for (int m=0;m<2;++m) {
      int tt = w*2 + m;
      int t = tt*16 + cl;
      int s3 = t >> 5;
      int g23 = (t >> 2) & 3;
      int j3 = ((t >> 4) & 1)*4 + (t & 3);
      U8 va;
      #pragma unroll
      for (int jj=0;jj<4;++jj)
        va.u[jj] = VF[s3*512 + (g23*16 + 4*g + jj)*8 + j3];
      va.d[1] = make_uint2(0,0);
      f32x4 o; o = 0;
      o = __builtin_amdgcn_mfma_f32_16x16x32_bf16(va.v, bb.v, o, 0,0,0);
      #pragma unroll
      for (int r=0;r<4;++r) {
        int tr = tt*16 + g*4 + r;
        int t2 = hb*64 + (tr>>1), cb = (tr&1)*64 + h1*16 + cl;
        o2b[((size_t)(bn*128 + t2))*128 + cb] = f2bf(o[r]);
      }
      float s0 = o[0]+o[2], q0 = o[0]*o[0]+o[2]*o[2];
      float s1 = o[1]+o[3], q1 = o[1]*o[1]+o[3]*o[3];
      s0 += __shfl_xor(s0,16); s0 += __shfl_xor(s0,32);
      q0 += __shfl_xor(q0,16); q0 += __shfl_xor(q0,32);
      s1 += __shfl_xor(s1,16); s1 += __shfl_xor(s1,32);
      q1 += __shfl_xor(q1,16); q1 += __shfl_xor(q1,32);
      if (g == 0) {
        atomicAdd(&partp[64+cl],    s0);
        atomicAdd(&partp[64+16+cl], q0);
        atomicAdd(&partp[64+32+cl], s1);
        atomicAdd(&partp[64+48+cl], q1);
      }
    }
  }
  __syncthreads();
  if (tid < 128) p12[(size_t)(bn*8 + h)*128 + tid] = partp[tid];
}

// ---------------------------------------------------------------------------
// K-red12: tree-reduce p12[4096][128] -> q12[128][128]
// ---------------------------------------------------------------------------
__global__ __launch_bounds__(256) void k_red12(
    const float* __restrict__ p12, float* __restrict__ q12) {
  __shared__ float red[256];
  const int tid = threadIdx.x;
  const int slot = tid & 127, half = tid >> 7;
  const int h = blockIdx.x & 7, chunk = blockIdx.x >> 3;
  float s = 0.f;
  for (int t = half; t < 32; t += 2)
    s += p12[(size_t)((chunk*32 + t)*8 + h)*128 + slot];
  red[tid] = s;
  __syncthreads();
  if (tid < 128)
    q12[(size_t)blockIdx.x*128 + tid] = red[tid] + red[tid + 128];
}

// K4: finalize bn1/bn2 from q12 (64KB, L2-resident)
__global__ __launch_bounds__(256) void k_fin12(
    const float* __restrict__ q12,
    const float* __restrict__ g1, const float* __restrict__ b1,
    const float* __restrict__ g2, const float* __restrict__ b2,
    float* __restrict__ stats) {
  const int tid = threadIdx.x;       // 0..255
  const int br = tid >> 7, c = tid & 127;
  const int grp = c >> 6, h1 = (c & 63) >> 4, cl = c & 15;
  const int slot = br*64 + grp*32 + cl;
  float s = 0.f, q = 0.f;
  #pragma unroll 4
  for (int chunk = 0; chunk < 16; ++chunk) {
    const float* p0 = &q12[(size_t)(chunk*8 + h1*2)*128];
    s += p0[slot]      + p0[128 + slot];
    q += p0[slot + 16] + p0[128 + slot + 16];
  }
  const float inv = 1.0f/65536.0f;
  float m = s*inv, v = q*inv - m*m;
  float r = rsqrtf(v + 1e-5f);
  float gv = br ? g2[c] : g1[c];
  float bv = br ? b2[c] : b1[c];
  float sc = r * gv;
  stats[br*256 + c]       = sc;
  stats[br*256 + 128 + c] = bv - m*sc;
}

// ---------------------------------------------------------------------------
// K5: fused dual FFN, bf16 MFMA. Writes bf16 pre-bn3 (outb) + p3 partials
// computed on the ROUNDED values. __launch_bounds__(512,3): 3 blocks/CU ->
// VGPR cap 85 >= natural 76 (no spill) AND 24 waves/CU floor.
// ((512,4) capped at 64 -> 46MB spill; (512,2) no-spill but occ 22%.)
// ---------------------------------------------------------------------------
__global__ __launch_bounds__(512, 3) void k_ff(
    const unsigned short* __restrict__ o1b, const unsigned short* __restrict__ o2b,
    const float* __restrict__ src,
    const float* __restrict__ bb11, const float* __restrict__ bb12,
    const float* __restrict__ bb21, const float* __restrict__ bb22,
    const unsigned short* __restrict__ wf,
    const float* __restrict__ stats, unsigned short* __restrict__ outb,
    float* __restrict__ p3) {
  __shared__ __align__(16) unsigned short Xbf[64*128];  // 16 KB
  __shared__ __align__(16) unsigned short Hbf[64*128];  // 16 KB
  const int tid = threadIdx.x;
  const int lane = tid & 63, w = tid >> 6;          // w = 0..7
  const int cl = lane & 15, g = lane >> 4;
  const size_t rb = (size_t)blockIdx.x * 64;

  f32x4 acc2[4];
  #pragma unroll
  for (int m=0;m<4;++m) acc2[m] = 0;

  for (int br=0; br<2; ++br) {
    const unsigned short* xin = br ? o2b : o1b;
    const float* sc_ = stats + br*256;
    const float* sh_ = sc_ + 128;
    const unsigned short* w1f = wf + br*65536;
    const unsigned short* w2f = w1f + 32768;
    const float* b1g = br ? bb21 : bb11;

    __syncthreads();
    #pragma unroll
    for (int it=0; it<4; ++it) {
      int idx = it*512 + tid;
      int row = idx >> 5, c4 = (idx & 31)*4;
      uint2 u = *(const uint2*)&xin[(rb+row)*128 + c4];
      float x0 = bf2f((unsigned short)(u.x & 0xffff));
      float x1 = bf2f((unsigned short)(u.x >> 16));
      float x2 = bf2f((unsigned short)(u.y & 0xffff));
      float x3 = bf2f((unsigned short)(u.y >> 16));
      unsigned int lo = f2bf(fmaf(x0, sc_[c4+0], sh_[c4+0]))
                      | ((unsigned int)f2bf(fmaf(x1, sc_[c4+1], sh_[c4+1])) << 16);
      unsigned int hi = f2bf(fmaf(x2, sc_[c4+2], sh_[c4+2]))
                      | ((unsigned int)f2bf(fmaf(x3, sc_[c4+3], sh_[c4+3])) << 16);
      unsigned int byteo = (unsigned)((row*256 + c4*2) ^ ((row&7)<<4));
      *(uint2*)((char*)Xbf + byteo) = make_uint2(lo, hi);
    }
    __syncthreads();

    #pragma unroll
    for (int hc=0; hc<2; ++hc) {
      f32x4 acc1[4];
      #pragma unroll
      for (int m=0;m<4;++m) acc1[m] = 0;

      bf16x8 bfs[4];
      #pragma unroll
      for (int s=0; s<4; ++s) {
        int n = hc*128 + w*16 + cl;
        bfs[s] = *(const bf16x8*)(w1f + (size_t)((s*256 + n)*4 + g)*8);
      }
      #pragma unroll
      for (int s=0; s<4; ++s) {
        #pragma unroll
        for (int m=0; m<4; ++m) {
          int row = m*16 + cl;
          U8 u;
          u.d[0] = *(uint2*)((char*)Xbf + (unsigned)((row*256 + (s*32 + g*4)*2)    ^ ((row&7)<<4)));
          u.d[1] = *(uint2*)((char*)Xbf + (unsigned)((row*256 + (s*32 +16+ g*4)*2) ^ ((row&7)<<4)));
          acc1[m] = __builtin_amdgcn_mfma_f32_16x16x32_bf16(u.v, bfs[s], acc1[m], 0, 0, 0);
        }
      }

      {
        int col = w*16 + cl;
        float bias = b1g[hc*128 + col];
        #pragma unroll
        for (int m=0; m<4; ++m) {
          #pragma unroll
          for (int r=0; r<4; ++r) {
            float y = gelu_f(acc1[m][r] + bias);
            int row = m*16 + g*4 + r;
            unsigned int byteo = (unsigned)((row*256 + col*2) ^ ((row&7)<<4));
            *(unsigned short*)((char*)Hbf + byteo) = f2bf(y);
          }
        }
      }
      __syncthreads();

      bf16x8 bf2[4];
      #pragma unroll
      for (int s2l=0; s2l<4; ++s2l) {
        int s2 = hc*4 + s2l;
        int n = w*16 + cl;
        bf2[s2l] = *(const bf16x8*)(w2f + (size_t)((s2*128 + n)*4 + g)*8);
      }
      #pragma unroll
      for (int s2l=0; s2l<4; ++s2l) {
        #pragma unroll
        for (int m=0; m<4; ++m) {
          int row = m*16 + cl;
          U8 u;
          u.d[0] = *(uint2*)((char*)Hbf + (unsigned)((row*256 + (s2l*32 + g*4)*2)    ^ ((row&7)<<4)));
          u.d[1] = *(uint2*)((char*)Hbf + (unsigned)((row*256 + (s2l*32 +16+ g*4)*2) ^ ((row&7)<<4)));
          acc2[m] = __builtin_amdgcn_mfma_f32_16x16x32_bf16(u.v, bf2[s2l], acc2[m], 0, 0, 0);
        }
      }
      __syncthreads();
    }
  }

  {
    int col = w*16 + cl;
    float bias = bb12[col] + bb22[col];
    float cs = 0.f, cq = 0.f;
    #pragma unroll
    for (int m=0; m<4; ++m) {
      #pragma unroll
      for (int r=0; r<4; ++r) {
        size_t row = rb + m*16 + g*4 + r;
        float o = src[row*128 + col] + acc2[m][r] + bias;
        unsigned short ob = f2bf(o);
        outb[row*128 + col] = ob;
        float orv = bf2f(ob);           // stats on rounded value
        cs += orv; cq = fmaf(orv, orv, cq);
      }
    }
    cs += __shfl_down(cs, 32); cs += __shfl_down(cs, 16);
    cq += __shfl_down(cq, 32); cq += __shfl_down(cq, 16);
    if (g == 0) {
      p3[(size_t)blockIdx.x*256 + col]       = cs;
      p3[(size_t)blockIdx.x*256 + 128 + col] = cq;
    }
  }
}

// K-red3: tree-reduce p3[1024][256] -> q3[32][256]
__global__ __launch_bounds__(256) void k_red3(
    const float* __restrict__ p3, float* __restrict__ q3) {
  const int tid = threadIdx.x;
  float s = 0.f;
  const int b0 = blockIdx.x*32;
  for (int b = b0; b < b0 + 32; ++b)
    s += p3[(size_t)b*256 + tid];
  q3[(size_t)blockIdx.x*256 + tid] = s;
}

// K6: finalize bn3 from q3 (32KB)
__global__ __launch_bounds__(256) void k_fin3(
    const float* __restrict__ q3, const float* __restrict__ g3,
    const float* __restrict__ b3, float* __restrict__ stats) {
  __shared__ float acc[256];
  const int tid = threadIdx.x;
  float s = 0.f;
  #pragma unroll 4
  for (int i = 0; i < 32; ++i) s += q3[i*256 + tid];
  acc[tid] = s;
  __syncthreads();
  if (tid < 128) {
    const float inv = 1.0f/65536.0f;
    float m = acc[tid]*inv, v = acc[128+tid]*inv - m*m;
    float r = rsqrtf(v + 1e-5f);
    float scv = r*g3[tid];
    stats[512 + tid] = scv;
    stats[640 + tid] = b3[tid] - m*scv;
  }
}

// K7: final batchnorm: bf16 pre-bn3 in, fp32 d_out out.
// 1048576 uint4-units total; 524288 threads x 2 iters.
__global__ __launch_bounds__(256) void k_bn3(
    const unsigned short* __restrict__ outb, const float* __restrict__ stats,
    float* __restrict__ outp) {
  const int i0 = blockIdx.x*256 + threadIdx.x;   // uint4 index (8 bf16)
  const int c0 = (i0 & 15) * 8;                  // channel base (524288%16==0)
  #pragma unroll
  for (int it=0; it<2; ++it) {
    size_t ui = (size_t)i0 + (size_t)it*524288;
    size_t eb = ui * 8;
    uint4 u = *(const uint4*)&outb[eb];
    unsigned int uu[4] = {u.x, u.y, u.z, u.w};
    float out[8];
    #pragma unroll
    for (int p=0; p<4; ++p) {
      float a = bf2f((unsigned short)(uu[p] & 0xffff));
      float b = bf2f((unsigned short)(uu[p] >> 16));
      out[p*2]   = fmaf(a, stats[512 + c0 + p*2],     stats[640 + c0 + p*2]);
      out[p*2+1] = fmaf(b, stats[512 + c0 + p*2 + 1], stats[640 + c0 + p*2 + 1]);
    }
    *(float4*)&outp[eb]     = make_float4(out[0], out[1], out[2], out[3]);
    *(float4*)&outp[eb + 4] = make_float4(out[4], out[5], out[6], out[7]);
  }
}

extern "C" void kernel_launch(void* const* d_in, const int* in_sizes, int n_in,
                              void* d_out, int out_size, void* d_ws, size_t ws_size,
                              hipStream_t stream) {
  const float* src   = (const float*)d_in[0];
  const float* qkv_w = (const float*)d_in[1];
  const float* qkv_b = (const float*)d_in[2];
  const float* ff1w1 = (const float*)d_in[3];
  const float* ff1b1 = (const float*)d_in[4];
  const float* ff1w2 = (const float*)d_in[5];
  const float* ff1b2 = (const float*)d_in[6];
  const float* ff2w1 = (const float*)d_in[7];
  const float* ff2b1 = (const float*)d_in[8];
  const float* ff2w2 = (const float*)d_in[9];
  const float* ff2b2 = (const float*)d_in[10];
  const float* g1 = (const float*)d_in[11];
  const float* b1 = (const float*)d_in[12];
  const float* g2 = (const float*)d_in[13];
  const float* b2 = (const float*)d_in[14];
  const float* g3 = (const float*)d_in[15];
  const float* b3 = (const float*)d_in[16];
  const float* ema = (const float*)d_in[17];

  float* ws = (float*)d_ws;
  unsigned short* o1b = (unsigned short*)ws;               // 8388608 bf16
  unsigned short* o2b = o1b + 8388608;
  float* p12 = (float*)(o2b + 8388608);  // 4096*128
  float* p3  = p12 + 524288;             // 1024*256
  float* stats = p3 + 262144;            // 768 (+pad)
  unsigned short* wfrag = (unsigned short*)(stats + 1024);  // 4*32768 bf16
  unsigned short* efrag = wfrag + 131072;                   // 16384 bf16
  unsigned short* wqh   = efrag + 16384;                    // 49152 bf16
  unsigned short* wql   = wqh + 49152;                      // 49152 bf16
  float* q12 = (float*)(wql + 49152);    // 128*128
  float* q3  = q12 + 16384;              // 32*256
  unsigned short* sfh = (unsigned short*)(q3 + 8192);       // 512*16384 bf16
  unsigned short* sfl = sfh + 8388608;
  unsigned short* outbb = sfl + 8388608;                    // 8388608 bf16
  float* outp = (float*)d_out;

  k_prep<<<dim3(608), dim3(256), 0, stream>>>(ff1w1, ff1w2, ff2w1, ff2w2, ema,
                                              qkv_w, src, wfrag, efrag,
                                              wqh, wql, sfh, sfl);
  k_qa<<<dim3(4096), dim3(256), 0, stream>>>(sfh, sfl, wqh, wql, qkv_b, efrag,
                                             o1b, o2b, p12);
  k_red12<<<dim3(128), dim3(256), 0, stream>>>(p12, q12);
  k_fin12<<<dim3(1), dim3(256), 0, stream>>>(q12, g1, b1, g2, b2, stats);
  k_ff<<<dim3(1024), dim3(512), 0, stream>>>(o1b, o2b, src,
      ff1b1, ff1b2, ff2b1, ff2b2, wfrag, stats, outbb, p3);
  k_red3<<<dim3(32), dim3(256), 0, stream>>>(p3, q3);
  k_fin3<<<dim3(1), dim3(256), 0, stream>>>(q3, g3, b3, stats);
  k_bn3<<<dim3(2048), dim3(256), 0, stream>>>(outbb, stats, outp);
}

// Round 25
// 170.577 us; speedup vs baseline: 1.0543x; 1.0532x over previous
//
#include <hip/hip_runtime.h>
#include <math.h>

// Problem constants
#define BN_ 512     // B*NVARS
#define T_  128
#define C_  128
#define H_  8
#define D_  16
#define F_  256
#define M_  65536   // BN_*T_

typedef __bf16 bf16x8 __attribute__((ext_vector_type(8)));
typedef float f32x4 __attribute__((ext_vector_type(4)));
union U8 { uint2 d[2]; bf16x8 v; unsigned short u[8]; };

// native f32->bf16 (RNE) -- lets compiler emit v_cvt_pk_bf16_f32
__device__ inline unsigned short f2bf(float x) {
  union { __bf16 b; unsigned short u; } c;
  c.b = (__bf16)x;
  return c.u;
}
__device__ inline float bf2f(unsigned short h) {
  return __uint_as_float((unsigned int)h << 16);
}
// exact-enough GELU: erf via A&S 7.1.26, |eps|<=1.5e-7
__device__ inline float gelu_f(float x) {
  float z  = x * 0.70710678118654752f;
  float az = fabsf(z);
  float t  = 1.0f / (1.0f + 0.3275911f * az);
  float poly = ((((1.061405429f*t - 1.453152027f)*t + 1.421413741f)*t
                 - 0.284496736f)*t + 0.254829592f)*t;
  float e  = __expf(-z*z);
  float er = 1.0f - poly*e;
  er = (z < 0.0f) ? -er : er;
  return 0.5f * x * (1.0f + er);
}

// ---------------------------------------------------------------------------
// K-prep: FFN weight frags (blocks 0..63), E frags (64..71),
//         qkv_w split hi/lo frags (72..95), src frags (96..607).
// ---------------------------------------------------------------------------
__global__ __launch_bounds__(256) void k_prep(
    const float* __restrict__ w11, const float* __restrict__ w12,
    const float* __restrict__ w21, const float* __restrict__ w22,
    const float* __restrict__ ema, const float* __restrict__ qkvw,
    const float* __restrict__ src,
    unsigned short* __restrict__ wf, unsigned short* __restrict__ ef,
    unsigned short* __restrict__ wqh, unsigned short* __restrict__ wql,
    unsigned short* __restrict__ sfh, unsigned short* __restrict__ sfl) {
  if (blockIdx.x >= 96) {
    const int bn = blockIdx.x - 96;
    const int tid = threadIdx.x;
    #pragma unroll
    for (int it=0; it<8; ++it) {
      int uidx = it*256 + tid;          // 0..2047
      int half = uidx >> 10;
      int tile = (uidx >> 6) & 15;
      int u    = uidx & 63;
      int rq = tile >> 2, s = tile & 3;
      int g2 = u >> 4, r15 = u & 15;
      int r  = half*64 + rq*16 + r15;   // 0..127
      const float* sp = &src[((size_t)bn*128 + r)*128 + s*32 + g2*4];
      float4 v0 = *(const float4*)sp;
      float4 v1 = *(const float4*)(sp + 16);
      float vv[8] = {v0.x,v0.y,v0.z,v0.w,v1.x,v1.y,v1.z,v1.w};
      unsigned short hh[8], ll[8];
      #pragma unroll
      for (int j=0;j<8;++j) {
        hh[j] = f2bf(vv[j]);
        ll[j] = f2bf(vv[j] - bf2f(hh[j]));
      }
      size_t off = (size_t)bn*16384 + (size_t)uidx*8;
      *(uint4*)(sfh + off) = *(uint4*)hh;
      *(uint4*)(sfl + off) = *(uint4*)ll;
    }
    return;
  }
  if (blockIdx.x >= 72) {
    int tid3 = (blockIdx.x - 72)*256 + threadIdx.x;   // 0..6143
    int s = tid3 / 1536;
    int rem = tid3 - s*1536;
    int n = rem >> 2, g = rem & 3;
    size_t fi = (size_t)((s*384 + n)*4 + g)*8;
    #pragma unroll
    for (int j=0;j<8;++j) {
      int k = 32*s + 16*(j>>2) + 4*g + (j&3);
      float v = qkvw[(size_t)k*384 + n];
      unsigned short h = f2bf(v);
      wqh[fi+j] = h;
      wql[fi+j] = f2bf(v - bf2f(h));
    }
    return;
  }
  if (blockIdx.x >= 64) {
    int tid2 = (blockIdx.x - 64)*256 + threadIdx.x;   // 0..2047
    int mt = tid2 >> 8, s = (tid2 >> 6) & 3, lane = tid2 & 63;
    int cl = lane & 15, g = lane >> 4;
    unsigned short* dst = ef + (size_t)tid2*8;
    #pragma unroll
    for (int j=0;j<8;++j) {
      int k = 32*s + 16*(j>>2) + 4*g + (j&3);
      dst[j] = f2bf(ema[(size_t)(mt*16 + cl)*128 + k]);
    }
    return;
  }
  int tid = blockIdx.x*256 + threadIdx.x;   // 16384 total
  int m = tid >> 12;
  int idx = tid & 4095;
  const float* w; int N;
  if (m==0)      { w = w11; N = 256; }
  else if (m==1) { w = w12; N = 128; }
  else if (m==2) { w = w21; N = 256; }
  else           { w = w22; N = 128; }
  int g  = idx & 3;
  int sn = idx >> 2;
  int n  = (N==256) ? (sn & 255) : (sn & 127);
  int s  = (N==256) ? (sn >> 8)  : (sn >> 7);
  unsigned short* dst = wf + m*32768 + idx*8;
  #pragma unroll
  for (int j=0; j<8; ++j) {
    int k = s*32 + g*4 + (j&3) + 16*(j>>2);
    dst[j] = f2bf(w[(size_t)k*N + n]);
  }
}

// ---------------------------------------------------------------------------
// K-QA: fused QKV projection + per-(bn,h) attention (round-18 structure).
// ---------------------------------------------------------------------------
__global__ __launch_bounds__(256, 5) void k_qa(
    const unsigned short* __restrict__ sfh, const unsigned short* __restrict__ sfl,
    const unsigned short* __restrict__ wqh, const unsigned short* __restrict__ wql,
    const float* __restrict__ qbias, const unsigned short* __restrict__ ef,
    unsigned short* __restrict__ o1b, unsigned short* __restrict__ o2b,
    float* __restrict__ p12) {
  __shared__ __align__(16) unsigned short QFh[2048], QFl[2048];
  __shared__ __align__(16) unsigned short KFh[2048], KFl[2048];
  __shared__ __align__(16) unsigned short VF[2048];
  __shared__ __align__(16) unsigned short eqL[2560], ekL[2560];  // stride 20
  __shared__ __align__(16) float s2L[16*16];
  __shared__ float partp[128];

  const int tid = threadIdx.x;
  const int lane = tid & 63, w = tid >> 6;
  const int cl = lane & 15, g = lane >> 4;
  const int bid = blockIdx.x;
  const int bn = (bid & 7)*64 + (bid >> 6);
  const int h  = (bid >> 3) & 7;
  const int h1 = h >> 1, hb = h & 1;

  if (tid < 128) partp[tid] = 0.f;

  // ---- Phase 0: QKV projection, s-outer / half-inner, batched loads ----
  const float bq = qbias[h*16 + cl];
  const float bk = qbias[128 + h*16 + cl];
  const float bv = qbias[256 + h*16 + cl];
  const unsigned short* gh = sfh + (size_t)bn*16384;
  const unsigned short* gl = sfl + (size_t)bn*16384;
  {
    f32x4 acc[2][3];
    #pragma unroll
    for (int hf=0; hf<2; ++hf)
      #pragma unroll
      for (int nt=0; nt<3; ++nt) acc[hf][nt] = 0;

    #pragma unroll
    for (int s=0; s<4; ++s) {
      bf16x8 bh[3], bl[3];
      #pragma unroll
      for (int nt=0; nt<3; ++nt) {
        int n = nt*128 + h*16 + cl;
        size_t fi = (size_t)((s*384 + n)*4 + g)*8;
        bh[nt] = *(const bf16x8*)(wqh + fi);
        bl[nt] = *(const bf16x8*)(wql + fi);
      }
      size_t a0 = (size_t)((w*4+s)*512 + lane*8);
      bf16x8 ah0 = *(const bf16x8*)&gh[a0];
      bf16x8 al0 = *(const bf16x8*)&gl[a0];
      bf16x8 ah1 = *(const bf16x8*)&gh[a0 + 8192];
      bf16x8 al1 = *(const bf16x8*)&gl[a0 + 8192];
      #pragma unroll
      for (int nt=0; nt<3; ++nt) {
        acc[0][nt] = __builtin_amdgcn_mfma_f32_16x16x32_bf16(ah0, bh[nt], acc[0][nt], 0,0,0);
        acc[0][nt] = __builtin_amdgcn_mfma_f32_16x16x32_bf16(ah0, bl[nt], acc[0][nt], 0,0,0);
        acc[0][nt] = __builtin_amdgcn_mfma_f32_16x16x32_bf16(al0, bh[nt], acc[0][nt], 0,0,0);
        acc[1][nt] = __builtin_amdgcn_mfma_f32_16x16x32_bf16(ah1, bh[nt], acc[1][nt], 0,0,0);
        acc[1][nt] = __builtin_amdgcn_mfma_f32_16x16x32_bf16(ah1, bl[nt], acc[1][nt], 0,0,0);
        acc[1][nt] = __builtin_amdgcn_mfma_f32_16x16x32_bf16(al1, bh[nt], acc[1][nt], 0,0,0);
      }
    }
    #pragma unroll
    for (int hf=0; hf<2; ++hf) {
      const int tb = hf*64 + w*16 + g*4;
      #pragma unroll
      for (int r=0; r<4; ++r) {
        int t = tb + r;
        int s_t = t >> 5, kk = t & 31;
        int g2 = (kk >> 2) & 3, j = ((kk >> 4) << 2) | (kk & 3);
        int fi = s_t*512 + (g2*16 + cl)*8 + j;
        float qv = acc[hf][0][r] + bq;
        unsigned short qh = f2bf(qv);
        QFh[fi] = qh; QFl[fi] = f2bf(qv - bf2f(qh));
        float kv = acc[hf][1][r] + bk;
        unsigned short kh = f2bf(kv);
        KFh[fi] = kh; KFl[fi] = f2bf(kv - bf2f(kh));
        VF[fi] = f2bf(acc[hf][2][r] + bv);
      }
    }
  }
  __syncthreads();   // all fragments visible

  // ---- Phase 1: eq = E@Q, ek = E@K; wave 3 also s_hid + softmax ----
  {
    f32x4 aq[2], ak[2];
    #pragma unroll
    for (int m=0;m<2;++m){ aq[m]=0; ak[m]=0; }
    #pragma unroll
    for (int s=0;s<4;++s) {
      bf16x8 qf = *(const bf16x8*)&QFh[s*512 + lane*8];
      bf16x8 kf = *(const bf16x8*)&KFh[s*512 + lane*8];
      #pragma unroll
      for (int m=0;m<2;++m) {
        int mt = w*2 + m;
        bf16x8 eA = *(const bf16x8*)&ef[(size_t)((mt*4 + s)*64 + lane)*8];
        aq[m] = __builtin_amdgcn_mfma_f32_16x16x32_bf16(eA, qf, aq[m], 0,0,0);
        ak[m] = __builtin_amdgcn_mfma_f32_16x16x32_bf16(eA, kf, ak[m], 0,0,0);
      }
    }
    #pragma unroll
    for (int m=0;m<2;++m)
      #pragma unroll
      for (int r=0;r<4;++r) {
        int row = w*32 + m*16 + g*4 + r;
        eqL[row*20 + cl] = f2bf(aq[m][r]);
        ekL[row*20 + cl] = f2bf(ak[m][r]);
      }
  }
  if (w == 3) {
    f32x4 a2; a2 = 0;
    #pragma unroll
    for (int s=0;s<4;++s) {
      bf16x8 qh = *(const bf16x8*)&QFh[s*512 + lane*8];
      bf16x8 ql = *(const bf16x8*)&QFl[s*512 + lane*8];
      bf16x8 kh = *(const bf16x8*)&KFh[s*512 + lane*8];
      bf16x8 kl = *(const bf16x8*)&KFl[s*512 + lane*8];
      a2 = __builtin_amdgcn_mfma_f32_16x16x32_bf16(qh, kh, a2, 0,0,0);
      a2 = __builtin_amdgcn_mfma_f32_16x16x32_bf16(qh, kl, a2, 0,0,0);
      a2 = __builtin_amdgcn_mfma_f32_16x16x32_bf16(ql, kh, a2, 0,0,0);
    }
    const float CH = 11.313708498984761f * 1.4426950408889634f;
    #pragma unroll
    for (int r=0;r<4;++r) {
      float sv = a2[r];
      float mx = sv;
      mx = fmaxf(mx, __shfl_xor(mx, 1));
      mx = fmaxf(mx, __shfl_xor(mx, 2));
      mx = fmaxf(mx, __shfl_xor(mx, 4));
      mx = fmaxf(mx, __shfl_xor(mx, 8));
      float p = exp2f(fmaf(sv, CH, -mx*CH));
      float sum = p;
      sum += __shfl_xor(sum, 1);
      sum += __shfl_xor(sum, 2);
      sum += __shfl_xor(sum, 4);
      sum += __shfl_xor(sum, 8);
      s2L[(g*4 + r)*16 + cl] = p / sum;
    }
  }
  __syncthreads();

  // ---- Phase 2: token attention (S^T = ek@eq^T, exp2 softmax, deferred inv) ----
  {
    f32x4 accS[8][2];
    #pragma unroll
    for (int kt=0;kt<8;++kt)
      #pragma unroll
      for (int qt=0;qt<2;++qt) accS[kt][qt] = 0;
    U8 eb[2];
    #pragma unroll
    for (int qt=0;qt<2;++qt) {
      eb[qt].d[0] = *(const uint2*)&eqL[(w*32 + qt*16 + cl)*20 + 4*g];
      eb[qt].d[1] = make_uint2(0,0);
    }
    #pragma unroll
    for (int kt=0;kt<8;++kt) {
      U8 ea;
      ea.d[0] = *(const uint2*)&ekL[(kt*16 + cl)*20 + 4*g];
      ea.d[1] = make_uint2(0,0);
      #pragma unroll
      for (int qt=0;qt<2;++qt)
        accS[kt][qt] = __builtin_amdgcn_mfma_f32_16x16x32_bf16(ea.v, eb[qt].v, accS[kt][qt], 0,0,0);
    }
    bf16x8 vfr[4];
    #pragma unroll
    for (int s=0;s<4;++s) vfr[s] = *(const bf16x8*)&VF[s*512 + lane*8];
    const float CE = 4.0f * 1.4426950408889634f;
    #pragma unroll
    for (int qt=0;qt<2;++qt) {
      float mx = -1e30f;
      #pragma unroll
      for (int kt=0;kt<8;++kt)
        #pragma unroll
        for (int r=0;r<4;++r)
          mx = fmaxf(mx, accS[kt][qt][r]);
      mx = fmaxf(mx, __shfl_xor(mx, 16));
      mx = fmaxf(mx, __shfl_xor(mx, 32));
      float mxc = mx * CE;
      float sum = 0.f;
      #pragma unroll
      for (int kt=0;kt<8;++kt)
        #pragma unroll
        for (int r=0;r<4;++r) {
          float p = exp2f(fmaf(accS[kt][qt][r], CE, -mxc));
          accS[kt][qt][r] = p; sum += p;
        }
      sum += __shfl_xor(sum, 16);
      sum += __shfl_xor(sum, 32);
      float invq = 1.0f / sum;      // for q-col = cl
      f32x4 o; o = 0;
      #pragma unroll
      for (int s=0;s<4;++s) {
        U8 pa;
        #pragma unroll
        for (int j=0;j<8;++j)
          pa.u[j] = f2bf(accS[2*s + (j>>2)][qt][j&3]);
        o = __builtin_amdgcn_mfma_f32_16x16x32_bf16(pa.v, vfr[s], o, 0,0,0);
      }
      float ov[4];
      #pragma unroll
      for (int r=0;r<4;++r) {
        float invr = __shfl(invq, g*4 + r);   // lane g*4+r holds inv for that q-row
        ov[r] = o[r] * invr;
        int e = w*32 + qt*16 + g*4 + r;
        int t2 = hb*64 + (e>>1), cb = (e&1)*64 + h1*16 + cl;
        o1b[((size_t)(bn*128 + t2))*128 + cb] = f2bf(ov[r]);
      }
      float s0 = ov[0]+ov[2], q0 = ov[0]*ov[0]+ov[2]*ov[2];
      float s1 = ov[1]+ov[3], q1 = ov[1]*ov[1]+ov[3]*ov[3];
      s0 += __shfl_xor(s0,16); s0 += __shfl_xor(s0,32);
      q0 += __shfl_xor(q0,16); q0 += __shfl_xor(q0,32);
      s1 += __shfl_xor(s1,16); s1 += __shfl_xor(s1,32);
      q1 += __shfl_xor(q1,16); q1 += __shfl_xor(q1,32);
      if (g == 0) {
        atomicAdd(&partp[cl],      s0);
        atomicAdd(&partp[16+cl],   q0);
        atomicAdd(&partp[32+cl],   s1);
        atomicAdd(&partp[48+cl],   q1);
      }
    }
  }

  // ---- Phase 3: O2 = V @ A2^T (V A-frag derived from VF) ----
  {
    U8 bb;
    #pragma unroll
    for (int j=0;j<4;++j) bb.u[j] = f2bf(s2L[cl*16 + 4*g + j]);
    bb.d[1] = make_uint2(0,0);
    #pragma unroll
    for (int m=0;m<2;++m) {
      int tt = w*2 + m;
      int t = tt*16 + cl;
      int s3 = t >> 5;
      int g23 = (t >> 2) & 3;
      int j3 = ((t >> 4) & 1)*4 + (t & 3);
      U8 va;
      #pragma unroll
      for (int jj=0;jj<4;++jj)
        va.u[jj] = VF[s3*512 + (g23*16 + 4*g + jj)*8 + j3];
      va.d[1] = make_uint2(0,0);
      f32x4 o; o = 0;
      o = __builtin_amdgcn_mfma_f32_16x16x32_bf16(va.v, bb.v, o, 0,0,0);
      #pragma unroll
      for (int r=0;r<4;++r) {
        int tr = tt*16 + g*4 + r;
        int t2 = hb*64 + (tr>>1), cb = (tr&1)*64 + h1*16 + cl;
        o2b[((size_t)(bn*128 + t2))*128 + cb] = f2bf(o[r]);
      }
      float s0 = o[0]+o[2], q0 = o[0]*o[0]+o[2]*o[2];
      float s1 = o[1]+o[3], q1 = o[1]*o[1]+o[3]*o[3];
      s0 += __shfl_xor(s0,16); s0 += __shfl_xor(s0,32);
      q0 += __shfl_xor(q0,16); q0 += __shfl_xor(q0,32);
      s1 += __shfl_xor(s1,16); s1 += __shfl_xor(s1,32);
      q1 += __shfl_xor(q1,16); q1 += __shfl_xor(q1,32);
      if (g == 0) {
        atomicAdd(&partp[64+cl],    s0);
        atomicAdd(&partp[64+16+cl], q0);
        atomicAdd(&partp[64+32+cl], s1);
        atomicAdd(&partp[64+48+cl], q1);
      }
    }
  }
  __syncthreads();
  if (tid < 128) p12[(size_t)(bn*8 + h)*128 + tid] = partp[tid];
}

// ---------------------------------------------------------------------------
// K-red12: tree-reduce p12[4096][128] -> q12[128][128]
// ---------------------------------------------------------------------------
__global__ __launch_bounds__(256) void k_red12(
    const float* __restrict__ p12, float* __restrict__ q12) {
  __shared__ float red[256];
  const int tid = threadIdx.x;
  const int slot = tid & 127, half = tid >> 7;
  const int h = blockIdx.x & 7, chunk = blockIdx.x >> 3;
  float s = 0.f;
  for (int t = half; t < 32; t += 2)
    s += p12[(size_t)((chunk*32 + t)*8 + h)*128 + slot];
  red[tid] = s;
  __syncthreads();
  if (tid < 128)
    q12[(size_t)blockIdx.x*128 + tid] = red[tid] + red[tid + 128];
}

// K4: finalize bn1/bn2 from q12 (64KB, L2-resident)
__global__ __launch_bounds__(256) void k_fin12(
    const float* __restrict__ q12,
    const float* __restrict__ g1, const float* __restrict__ b1,
    const float* __restrict__ g2, const float* __restrict__ b2,
    float* __restrict__ stats) {
  const int tid = threadIdx.x;       // 0..255
  const int br = tid >> 7, c = tid & 127;
  const int grp = c >> 6, h1 = (c & 63) >> 4, cl = c & 15;
  const int slot = br*64 + grp*32 + cl;
  float s = 0.f, q = 0.f;
  #pragma unroll 4
  for (int chunk = 0; chunk < 16; ++chunk) {
    const float* p0 = &q12[(size_t)(chunk*8 + h1*2)*128];
    s += p0[slot]      + p0[128 + slot];
    q += p0[slot + 16] + p0[128 + slot + 16];
  }
  const float inv = 1.0f/65536.0f;
  float m = s*inv, v = q*inv - m*m;
  float r = rsqrtf(v + 1e-5f);
  float gv = br ? g2[c] : g1[c];
  float bv = br ? b2[c] : b1[c];
  float sc = r * gv;
  stats[br*256 + c]       = sc;
  stats[br*256 + 128 + c] = bv - m*sc;
}

// ---------------------------------------------------------------------------
// K5: fused dual FFN, bf16 MFMA. Writes bf16 pre-bn3 (outb) + p3 partials
// computed on the ROUNDED values. __launch_bounds__(512,4): measured best
// (75us; spilled-but-occupied beats no-spill variants (512,2)=82, (512,3)=82).
// ---------------------------------------------------------------------------
__global__ __launch_bounds__(512, 4) void k_ff(
    const unsigned short* __restrict__ o1b, const unsigned short* __restrict__ o2b,
    const float* __restrict__ src,
    const float* __restrict__ bb11, const float* __restrict__ bb12,
    const float* __restrict__ bb21, const float* __restrict__ bb22,
    const unsigned short* __restrict__ wf,
    const float* __restrict__ stats, unsigned short* __restrict__ outb,
    float* __restrict__ p3) {
  __shared__ __align__(16) unsigned short Xbf[64*128];  // 16 KB
  __shared__ __align__(16) unsigned short Hbf[64*128];  // 16 KB
  const int tid = threadIdx.x;
  const int lane = tid & 63, w = tid >> 6;          // w = 0..7
  const int cl = lane & 15, g = lane >> 4;
  const size_t rb = (size_t)blockIdx.x * 64;

  f32x4 acc2[4];
  #pragma unroll
  for (int m=0;m<4;++m) acc2[m] = 0;

  for (int br=0; br<2; ++br) {
    const unsigned short* xin = br ? o2b : o1b;
    const float* sc_ = stats + br*256;
    const float* sh_ = sc_ + 128;
    const unsigned short* w1f = wf + br*65536;
    const unsigned short* w2f = w1f + 32768;
    const float* b1g = br ? bb21 : bb11;

    __syncthreads();
    #pragma unroll
    for (int it=0; it<4; ++it) {
      int idx = it*512 + tid;
      int row = idx >> 5, c4 = (idx & 31)*4;
      uint2 u = *(const uint2*)&xin[(rb+row)*128 + c4];
      float x0 = bf2f((unsigned short)(u.x & 0xffff));
      float x1 = bf2f((unsigned short)(u.x >> 16));
      float x2 = bf2f((unsigned short)(u.y & 0xffff));
      float x3 = bf2f((unsigned short)(u.y >> 16));
      unsigned int lo = f2bf(fmaf(x0, sc_[c4+0], sh_[c4+0]))
                      | ((unsigned int)f2bf(fmaf(x1, sc_[c4+1], sh_[c4+1])) << 16);
      unsigned int hi = f2bf(fmaf(x2, sc_[c4+2], sh_[c4+2]))
                      | ((unsigned int)f2bf(fmaf(x3, sc_[c4+3], sh_[c4+3])) << 16);
      unsigned int byteo = (unsigned)((row*256 + c4*2) ^ ((row&7)<<4));
      *(uint2*)((char*)Xbf + byteo) = make_uint2(lo, hi);
    }
    __syncthreads();

    #pragma unroll
    for (int hc=0; hc<2; ++hc) {
      f32x4 acc1[4];
      #pragma unroll
      for (int m=0;m<4;++m) acc1[m] = 0;

      bf16x8 bfs[4];
      #pragma unroll
      for (int s=0; s<4; ++s) {
        int n = hc*128 + w*16 + cl;
        bfs[s] = *(const bf16x8*)(w1f + (size_t)((s*256 + n)*4 + g)*8);
      }
      #pragma unroll
      for (int s=0; s<4; ++s) {
        #pragma unroll
        for (int m=0; m<4; ++m) {
          int row = m*16 + cl;
          U8 u;
          u.d[0] = *(uint2*)((char*)Xbf + (unsigned)((row*256 + (s*32 + g*4)*2)    ^ ((row&7)<<4)));
          u.d[1] = *(uint2*)((char*)Xbf + (unsigned)((row*256 + (s*32 +16+ g*4)*2) ^ ((row&7)<<4)));
          acc1[m] = __builtin_amdgcn_mfma_f32_16x16x32_bf16(u.v, bfs[s], acc1[m], 0, 0, 0);
        }
      }

      {
        int col = w*16 + cl;
        float bias = b1g[hc*128 + col];
        #pragma unroll
        for (int m=0; m<4; ++m) {
          #pragma unroll
          for (int r=0; r<4; ++r) {
            float y = gelu_f(acc1[m][r] + bias);
            int row = m*16 + g*4 + r;
            unsigned int byteo = (unsigned)((row*256 + col*2) ^ ((row&7)<<4));
            *(unsigned short*)((char*)Hbf + byteo) = f2bf(y);
          }
        }
      }
      __syncthreads();

      bf16x8 bf2[4];
      #pragma unroll
      for (int s2l=0; s2l<4; ++s2l) {
        int s2 = hc*4 + s2l;
        int n = w*16 + cl;
        bf2[s2l] = *(const bf16x8*)(w2f + (size_t)((s2*128 + n)*4 + g)*8);
      }
      #pragma unroll
      for (int s2l=0; s2l<4; ++s2l) {
        #pragma unroll
        for (int m=0; m<4; ++m) {
          int row = m*16 + cl;
          U8 u;
          u.d[0] = *(uint2*)((char*)Hbf + (unsigned)((row*256 + (s2l*32 + g*4)*2)    ^ ((row&7)<<4)));
          u.d[1] = *(uint2*)((char*)Hbf + (unsigned)((row*256 + (s2l*32 +16+ g*4)*2) ^ ((row&7)<<4)));
          acc2[m] = __builtin_amdgcn_mfma_f32_16x16x32_bf16(u.v, bf2[s2l], acc2[m], 0, 0, 0);
        }
      }
      __syncthreads();
    }
  }

  {
    int col = w*16 + cl;
    float bias = bb12[col] + bb22[col];
    float cs = 0.f, cq = 0.f;
    #pragma unroll
    for (int m=0; m<4; ++m) {
      #pragma unroll
      for (int r=0; r<4; ++r) {
        size_t row = rb + m*16 + g*4 + r;
        float o = src[row*128 + col] + acc2[m][r] + bias;
        unsigned short ob = f2bf(o);
        outb[row*128 + col] = ob;
        float orv = bf2f(ob);           // stats on rounded value
        cs += orv; cq = fmaf(orv, orv, cq);
      }
    }
    cs += __shfl_down(cs, 32); cs += __shfl_down(cs, 16);
    cq += __shfl_down(cq, 32); cq += __shfl_down(cq, 16);
    if (g == 0) {
      p3[(size_t)blockIdx.x*256 + col]       = cs;
      p3[(size_t)blockIdx.x*256 + 128 + col] = cq;
    }
  }
}

// K-red3: tree-reduce p3[1024][256] -> q3[32][256]
__global__ __launch_bounds__(256) void k_red3(
    const float* __restrict__ p3, float* __restrict__ q3) {
  const int tid = threadIdx.x;
  float s = 0.f;
  const int b0 = blockIdx.x*32;
  for (int b = b0; b < b0 + 32; ++b)
    s += p3[(size_t)b*256 + tid];
  q3[(size_t)blockIdx.x*256 + tid] = s;
}

// K6: finalize bn3 from q3 (32KB)
__global__ __launch_bounds__(256) void k_fin3(
    const float* __restrict__ q3, const float* __restrict__ g3,
    const float* __restrict__ b3, float* __restrict__ stats) {
  __shared__ float acc[256];
  const int tid = threadIdx.x;
  float s = 0.f;
  #pragma unroll 4
  for (int i = 0; i < 32; ++i) s += q3[i*256 + tid];
  acc[tid] = s;
  __syncthreads();
  if (tid < 128) {
    const float inv = 1.0f/65536.0f;
    float m = acc[tid]*inv, v = acc[128+tid]*inv - m*m;
    float r = rsqrtf(v + 1e-5f);
    float scv = r*g3[tid];
    stats[512 + tid] = scv;
    stats[640 + tid] = b3[tid] - m*scv;
  }
}

// K7: final batchnorm: bf16 pre-bn3 in, fp32 d_out out.
// 1048576 uint4-units total; 524288 threads x 2 iters.
__global__ __launch_bounds__(256) void k_bn3(
    const unsigned short* __restrict__ outb, const float* __restrict__ stats,
    float* __restrict__ outp) {
  const int i0 = blockIdx.x*256 + threadIdx.x;   // uint4 index (8 bf16)
  const int c0 = (i0 & 15) * 8;                  // channel base (524288%16==0)
  #pragma unroll
  for (int it=0; it<2; ++it) {
    size_t ui = (size_t)i0 + (size_t)it*524288;
    size_t eb = ui * 8;
    uint4 u = *(const uint4*)&outb[eb];
    unsigned int uu[4] = {u.x, u.y, u.z, u.w};
    float out[8];
    #pragma unroll
    for (int p=0; p<4; ++p) {
      float a = bf2f((unsigned short)(uu[p] & 0xffff));
      float b = bf2f((unsigned short)(uu[p] >> 16));
      out[p*2]   = fmaf(a, stats[512 + c0 + p*2],     stats[640 + c0 + p*2]);
      out[p*2+1] = fmaf(b, stats[512 + c0 + p*2 + 1], stats[640 + c0 + p*2 + 1]);
    }
    *(float4*)&outp[eb]     = make_float4(out[0], out[1], out[2], out[3]);
    *(float4*)&outp[eb + 4] = make_float4(out[4], out[5], out[6], out[7]);
  }
}

extern "C" void kernel_launch(void* const* d_in, const int* in_sizes, int n_in,
                              void* d_out, int out_size, void* d_ws, size_t ws_size,
                              hipStream_t stream) {
  const float* src   = (const float*)d_in[0];
  const float* qkv_w = (const float*)d_in[1];
  const float* qkv_b = (const float*)d_in[2];
  const float* ff1w1 = (const float*)d_in[3];
  const float* ff1b1 = (const float*)d_in[4];
  const float* ff1w2 = (const float*)d_in[5];
  const float* ff1b2 = (const float*)d_in[6];
  const float* ff2w1 = (const float*)d_in[7];
  const float* ff2b1 = (const float*)d_in[8];
  const float* ff2w2 = (const float*)d_in[9];
  const float* ff2b2 = (const float*)d_in[10];
  const float* g1 = (const float*)d_in[11];
  const float* b1 = (const float*)d_in[12];
  const float* g2 = (const float*)d_in[13];
  const float* b2 = (const float*)d_in[14];
  const float* g3 = (const float*)d_in[15];
  const float* b3 = (const float*)d_in[16];
  const float* ema = (const float*)d_in[17];

  float* ws = (float*)d_ws;
  unsigned short* o1b = (unsigned short*)ws;               // 8388608 bf16
  unsigned short* o2b = o1b + 8388608;
  float* p12 = (float*)(o2b + 8388608);  // 4096*128
  float* p3  = p12 + 524288;             // 1024*256
  float* stats = p3 + 262144;            // 768 (+pad)
  unsigned short* wfrag = (unsigned short*)(stats + 1024);  // 4*32768 bf16
  unsigned short* efrag = wfrag + 131072;                   // 16384 bf16
  unsigned short* wqh   = efrag + 16384;                    // 49152 bf16
  unsigned short* wql   = wqh + 49152;                      // 49152 bf16
  float* q12 = (float*)(wql + 49152);    // 128*128
  float* q3  = q12 + 16384;              // 32*256
  unsigned short* sfh = (unsigned short*)(q3 + 8192);       // 512*16384 bf16
  unsigned short* sfl = sfh + 8388608;
  unsigned short* outbb = sfl + 8388608;                    // 8388608 bf16
  float* outp = (float*)d_out;

  k_prep<<<dim3(608), dim3(256), 0, stream>>>(ff1w1, ff1w2, ff2w1, ff2w2, ema,
                                              qkv_w, src, wfrag, efrag,
                                              wqh, wql, sfh, sfl);
  k_qa<<<dim3(4096), dim3(256), 0, stream>>>(sfh, sfl, wqh, wql, qkv_b, efrag,
                                             o1b, o2b, p12);
  k_red12<<<dim3(128), dim3(256), 0, stream>>>(p12, q12);
  k_fin12<<<dim3(1), dim3(256), 0, stream>>>(q12, g1, b1, g2, b2, stats);
  k_ff<<<dim3(1024), dim3(512), 0, stream>>>(o1b, o2b, src,
      ff1b1, ff1b2, ff2b1, ff2b2, wfrag, stats, outbb, p3);
  k_red3<<<dim3(32), dim3(256), 0, stream>>>(p3, q3);
  k_fin3<<<dim3(1), dim3(256), 0, stream>>>(q3, g3, b3, stats);
  k_bn3<<<dim3(2048), dim3(256), 0, stream>>>(outbb, stats, outp);
}